// Round 9
// baseline (131.562 us; speedup 1.0000x reference)
//
#include <hip/hip_runtime.h>
#include <hip/hip_bf16.h>

// KPConv MI355X — Round 9: intra-block software pipeline over half-tiles.
//   A(h0); bar; [prefetch A(h1)] B(h0); A(h1); bar; B(h1)
//   B(h) reads sF[h] while A(h^1) writes sF[h^1] — disjoint halves, no
//   extra barrier; phase-A VALU/TA overlaps phase-B DS/L2/MFMA.
// B=2, N=16384, M=16384, K=32, C_IN=64, C_OUT=128, KS=15, sigma=0.05.
//
// LDS per half (16-B chunks): off = j*2048 + u*256 + ((pl^(j&7))*16)
//   j = kernel pt 0..15 (15 pad), u = c-octet 0..7, pl = point 0..15.
// Phase A (wave = 2 points/half, pipelined gathers): influences in B-frag
//   layout (sentinel pad j=15), DPP row_ror normalize, feats uint2+v_perm;
//   one 16x16x32 bf16 MFMA per c-tile; D -> bf16 -> LDS.
// Phase B (wave = n-tile wv, M=16): 30 x (ds_read_b128 + W b128 + MFMA).

#define NB   16384
#define MB   16384
#define KN   32
#define CIN  64
#define COUT 128
#define KS   15
#define TP   32
#define WF_BYTES  245760u
#define FP_BYTES  (2u * MB * CIN * 2u)    // 4,194,304
#define SP4_BYTES (2u * MB * 16u)         //   524,288

typedef __attribute__((ext_vector_type(8))) short short8;
typedef __attribute__((ext_vector_type(4))) float f32x4;

// rotation-reduce step over the 16-lane DPP row: s += row_ror<n>(s)
#define ROR_ADD(s, ctrl) \
    ((s) + __int_as_float(__builtin_amdgcn_update_dpp( \
        0, __float_as_int(s), (ctrl), 0xF, 0xF, true)))

// bf16 pack (round-to-nearest, ties-away): low short = f0, high short = f1
static __device__ __forceinline__ unsigned int pack2_bf16(float f0, float f1) {
    const unsigned int a = __float_as_uint(f0) + 0x8000u;
    const unsigned int b = __float_as_uint(f1) + 0x8000u;
    return (a >> 16) | (b & 0xffff0000u);
}

static __device__ __forceinline__ unsigned int pack2_bf16_rne(float f0, float f1) {
    unsigned int a = __float_as_uint(f0);
    unsigned int b = __float_as_uint(f1);
    a += 0x7fffu + ((a >> 16) & 1u);
    b += 0x7fffu + ((b >> 16) & 1u);
    return (a >> 16) | (b & 0xffff0000u);
}

static __device__ __forceinline__ unsigned short f32_to_bf16_rne(float x) {
    unsigned int u = __float_as_uint(x);
    u += 0x7fffu + ((u >> 16) & 1u);
    return (unsigned short)(u >> 16);
}

__global__ __launch_bounds__(256)
void prep_kernel(const float* __restrict__ Wg, const float* __restrict__ feats,
                 const float* __restrict__ sp,
                 unsigned short* __restrict__ wf, unsigned int* __restrict__ fp,
                 float4* __restrict__ sp4, int full) {
    const int bid = blockIdx.x;
    if (bid < 60) {
        // W -> bf16 B-frag layout (15360 threads exactly)
        const int tid = bid * 256 + threadIdx.x;
        const int l = tid & 63;
        const int t = (tid >> 6) & 7;
        const int s = tid >> 9;
        const int n  = t * 16 + (l & 15);
        const int kb = s * 32 + (l >> 4) * 8;
        short8 o;
        #pragma unroll
        for (int i = 0; i < 8; ++i)
            o[i] = (short)f32_to_bf16_rne(Wg[(kb + i) * COUT + n]);
        *(short8*)(wf + (size_t)tid * 8) = o;
    } else if (!full) {
        return;
    } else if (bid < 60 + 128) {
        // support points -> float4 (32768 threads exactly)
        const int m = (bid - 60) * 256 + threadIdx.x;
        const float* s3 = sp + 3 * (size_t)m;
        sp4[m] = make_float4(s3[0], s3[1], s3[2], 0.0f);
    } else {
        // feats -> bf16 permuted: row m, position p=n16*4+t holds c=t*16+n16
        const unsigned int t = (unsigned int)(bid - 188) * 256u + threadIdx.x;
        if (t < 2u * MB * 32u) {          // u32 outputs: 32 per row
            const int m   = t >> 5;
            const int p2  = t & 31;       // output u32 = positions 2p2,2p2+1
            const int n16 = p2 >> 1;
            const int tt  = (p2 & 1) * 2;
            const float a = feats[(size_t)m * CIN + tt * 16 + n16];
            const float b = feats[(size_t)m * CIN + (tt + 1) * 16 + n16];
            fp[t] = pack2_bf16_rne(a, b);
        }
    }
}

template<bool PK>
__global__ __launch_bounds__(512, 4)
void kpconv_mfma(const float* __restrict__ qp,
                 const float* __restrict__ sp,
                 const float* __restrict__ feats,
                 const unsigned int* __restrict__ fpk,
                 const float4* __restrict__ sp4,
                 const int* __restrict__ nidx,
                 const float* __restrict__ kp,
                 const unsigned short* __restrict__ wfrag,
                 const float* __restrict__ bias,
                 float* __restrict__ out) {
    __shared__ __align__(16) char sF[2 * 32768];   // 65536 B -> 2 blocks/CU

    const int tid  = threadIdx.x;
    const int lane = tid & 63;
    const int wv   = tid >> 6;                 // 0..7
    const int gp_base = blockIdx.x * TP;
    const int b = gp_base >> 14;
    const float*        fbf  = feats + (size_t)b * MB * CIN;
    const unsigned int* fpb  = fpk + (size_t)b * MB * 32;       // 32 u32/row
    const float4*       sp4b = sp4 + (size_t)b * MB;
    const float*        spb  = sp + (size_t)b * MB * 3;

    const int n16  = lane & 15;     // j (A) / point row (B read) / o-sub (B out)
    const int quad = lane >> 4;     // k-group selector

    // kernel point for this lane's j; j==15 pad -> sentinel far away so
    // exp(-200*d2) underflows to exactly 0
    float kxj, kyj, kzj;
    if (n16 < 15) {
        kxj = kp[3 * n16 + 0];
        kyj = kp[3 * n16 + 1];
        kzj = kp[3 * n16 + 2];
    } else {
        kxj = 1.0e4f; kyj = 1.0e4f; kzj = 1.0e4f;
    }
    const float bsv = bias[wv * 16 + n16];

    int idxA[8], idxB[8];
    float4 s4A[8];

    // load the wave's point-pair indices for half h
    auto loadPair = [&](int h) {
        const int gp = gp_base + h * 16 + wv * 2;
        const int* ipp = nidx + (size_t)gp * KN + quad * 8;
        *(int4*)(&idxA[0]) = *(const int4*)(ipp);
        *(int4*)(&idxA[4]) = *(const int4*)(ipp + 4);
        *(int4*)(&idxB[0]) = *(const int4*)(ipp + KN);
        *(int4*)(&idxB[4]) = *(const int4*)(ipp + KN + 4);
    };

    auto gatherSp4 = [&](const int* idxv, float4* s4) {
        if (PK) {
            #pragma unroll
            for (int i = 0; i < 8; ++i) s4[i] = sp4b[idxv[i]];
        } else {
            #pragma unroll
            for (int i = 0; i < 8; ++i) {
                const float* s3 = spb + (size_t)idxv[i] * 3;
                s4[i] = make_float4(s3[0], s3[1], s3[2], 0.0f);
            }
        }
    };

    // one point: feat gathers, influences, normalize, frags, MFMA, LDS write
    auto aPoint = [&](const int* idxv, const float4* s4, int h, int plh, int gp) {
        uint2 g[8];
        if (PK) {
            #pragma unroll
            for (int i = 0; i < 8; ++i)
                g[i] = *(const uint2*)(fpb + (size_t)idxv[i] * 32 + n16 * 2);
        }

        const float qx = qp[3 * gp + 0];
        const float qy = qp[3 * gp + 1];
        const float qz = qp[3 * gp + 2];
        const float qkx = qx + kxj, qky = qy + kyj, qkz = qz + kzj;

        float e[8];
        #pragma unroll
        for (int i = 0; i < 8; ++i) {
            const float dx = s4[i].x - qkx;
            const float dy = s4[i].y - qky;
            const float dz = s4[i].z - qkz;
            const float d2 = fmaf(dx, dx, fmaf(dy, dy, dz * dz));
            e[i] = __expf(-200.0f * d2);   // 1/(2*sigma^2); j=15 -> 0
        }

        // normalize over j = 16-lane DPP row (pure VALU)
        unsigned int iu[4];
        float en[8];
        #pragma unroll
        for (int i = 0; i < 8; ++i) {
            float s = e[i];
            s = ROR_ADD(s, 0x128);   // row_ror:8
            s = ROR_ADD(s, 0x124);   // row_ror:4
            s = ROR_ADD(s, 0x122);   // row_ror:2
            s = ROR_ADD(s, 0x121);   // row_ror:1
            en[i] = e[i] * __builtin_amdgcn_rcpf(s + 1e-6f);
        }
        #pragma unroll
        for (int ih = 0; ih < 4; ++ih)
            iu[ih] = pack2_bf16(en[2 * ih], en[2 * ih + 1]);
        const short8 ifrag = *(const short8*)iu;

        // feats A-frags: elem i = feat[idx[quad*8+i]][c=t*16+n16]
        unsigned int fu[4][4];
        if (PK) {
            #pragma unroll
            for (int ih = 0; ih < 4; ++ih) {
                const unsigned int ax = g[2 * ih].x, bx = g[2 * ih + 1].x;
                const unsigned int ay = g[2 * ih].y, by = g[2 * ih + 1].y;
                fu[0][ih] = __builtin_amdgcn_perm(bx, ax, 0x05040100u);
                fu[1][ih] = __builtin_amdgcn_perm(bx, ax, 0x07060302u);
                fu[2][ih] = __builtin_amdgcn_perm(by, ay, 0x05040100u);
                fu[3][ih] = __builtin_amdgcn_perm(by, ay, 0x07060302u);
            }
        } else {
            #pragma unroll
            for (int ih = 0; ih < 4; ++ih) {
                const float* fr0 = fbf + (size_t)idxv[2 * ih]     * CIN + n16;
                const float* fr1 = fbf + (size_t)idxv[2 * ih + 1] * CIN + n16;
                #pragma unroll
                for (int t = 0; t < 4; ++t)
                    fu[t][ih] = pack2_bf16(fr0[t * 16], fr1[t * 16]);
            }
        }

        // MFMA per c-tile t; D[c_local=quad*4+r][j=n16] -> one b64 store:
        // chunk u = t*2+(quad>>1), half-chunk quad&1, row swizzle plh^(n16&7)
        char* base = sF + h * 32768;
        #pragma unroll
        for (int t = 0; t < 4; ++t) {
            const short8 ffrag = *(const short8*)(fu[t]);
            f32x4 z = {0.f, 0.f, 0.f, 0.f};
            const f32x4 dd = __builtin_amdgcn_mfma_f32_16x16x32_bf16(ffrag, ifrag, z, 0, 0, 0);
            const unsigned int lo = pack2_bf16(dd[0], dd[1]);
            const unsigned int hi = pack2_bf16(dd[2], dd[3]);
            const int off = n16 * 2048 + (t * 2 + (quad >> 1)) * 256 +
                            ((plh ^ (n16 & 7)) * 16) + (quad & 1) * 8;
            uint2 v; v.x = lo; v.y = hi;
            *(uint2*)(base + off) = v;                // ds_write_b64
        }
    };

    // A-stage for half h: pt0 (s4 in s4A), prefetch pt1 sp4, pt1
    auto aHalf = [&](int h) {
        float4 s4B[8];
        gatherSp4(idxB, s4B);          // issue early; hidden by pt0 compute
        aPoint(idxA, s4A, h, wv * 2,     gp_base + h * 16 + wv * 2);
        aPoint(idxB, s4B, h, wv * 2 + 1, gp_base + h * 16 + wv * 2 + 1);
    };

    // B-stage for half h: wave = n-tile wv, M=16 points
    auto bHalf = [&](int h) {
        f32x4 acc = {0.f, 0.f, 0.f, 0.f};
        const char* base = sF + h * 32768;
        #pragma unroll
        for (int s = 0; s < 30; ++s) {
            const int j = s >> 1;
            const int u = (s & 1) * 4 + quad;
            const short8 a  = *(const short8*)(base + j * 2048 + u * 256 +
                                               ((n16 ^ (j & 7)) * 16));
            const short8 bf = *(const short8*)(wfrag +
                                ((size_t)(s * 8 + wv) * 64 + lane) * 8);
            acc = __builtin_amdgcn_mfma_f32_16x16x32_bf16(a, bf, acc, 0, 0, 0);
        }
        #pragma unroll
        for (int r = 0; r < 4; ++r)
            out[(size_t)(gp_base + h * 16 + quad * 4 + r) * COUT + wv * 16 + n16]
                = acc[r] + bsv;
    };

    // ---------------- pipelined schedule ----------------
    loadPair(0);
    gatherSp4(idxA, s4A);
    aHalf(0);
    __syncthreads();

    loadPair(1);                 // prefetch A(h1) inputs...
    gatherSp4(idxA, s4A);        // ...their latency hides under B(h0)
    bHalf(0);                    // reads sF[0]; A(h1) writes sF[1] — disjoint
    aHalf(1);
    __syncthreads();

    bHalf(1);
}

extern "C" void kernel_launch(void* const* d_in, const int* in_sizes, int n_in,
                              void* d_out, int out_size, void* d_ws, size_t ws_size,
                              hipStream_t stream) {
    const float* qp = (const float*)d_in[0];   // query_points   [B,N,3]
    const float* sp = (const float*)d_in[1];   // support_points [B,M,3]
    const float* ft = (const float*)d_in[2];   // support_features [B,M,C_IN]
    const int*   ni = (const int*)d_in[3];     // neighbor_idx   [B,N,K]
    const float* kp = (const float*)d_in[4];   // kernel_points  [KS,3]
    const float* wg = (const float*)d_in[5];   // weights        [KS,C_IN,C_OUT]
    const float* bs = (const float*)d_in[6];   // bias           [C_OUT]
    float* o = (float*)d_out;                  // [B,N,C_OUT] fp32

    unsigned short* wfrag = (unsigned short*)d_ws;
    unsigned int*   fpk   = (unsigned int*)((char*)d_ws + WF_BYTES);
    float4*         sp4   = (float4*)((char*)d_ws + WF_BYTES + FP_BYTES);
    const int full = (ws_size >= (size_t)(WF_BYTES + FP_BYTES + SP4_BYTES)) ? 1 : 0;

    const int prep_blocks = full ? (60 + 128 + 4096) : 60;
    hipLaunchKernelGGL(prep_kernel, dim3(prep_blocks), dim3(256), 0, stream,
                       wg, ft, sp, wfrag, fpk, sp4, full);

    if (full) {
        hipLaunchKernelGGL((kpconv_mfma<true>), dim3((2 * NB) / TP), dim3(512), 0, stream,
                           qp, sp, ft, fpk, sp4, ni, kp, wfrag, bs, o);
    } else {
        hipLaunchKernelGGL((kpconv_mfma<false>), dim3((2 * NB) / TP), dim3(512), 0, stream,
                           qp, sp, ft, fpk, sp4, ni, kp, wfrag, bs, o);
    }
}

// Round 10
// 131.298 us; speedup vs baseline: 1.0020x; 1.0020x over previous
//
#include <hip/hip_runtime.h>
#include <hip/hip_bf16.h>

// KPConv MI355X — Round 10: R9's half-tile pipeline, spill-free.
//   A(h0); bar; [prefetch idx+sp4 h1] B(h0); A(h1); bar; B(h1)
// Implemented with macro-expanded straight-line code (no lambdas / no
// pointer-passed locals — R9's lambda pattern forced scratch spills:
// WRITE_SIZE 16->55 MB, VGPR 64). All arrays constant-indexed.
// B=2, N=16384, M=16384, K=32, C_IN=64, C_OUT=128, KS=15, sigma=0.05.
//
// LDS per half (16-B chunks): off = j*2048 + u*256 + ((pl^(j&7))*16)
//   j = kernel pt 0..15 (15 pad), u = c-octet 0..7, pl = point-in-half 0..15.
// Phase A (wave = 2 points per half): influences in B-frag layout
//   (sentinel pad j=15), DPP row_ror normalize, feats uint2 + v_perm;
//   one 16x16x32 bf16 MFMA per c-tile; D -> bf16 -> LDS (ds_write_b64).
// Phase B (wave = n-tile wv, M=16): 30 x (ds_read_b128 + W b128 + MFMA).

#define NB   16384
#define MB   16384
#define KN   32
#define CIN  64
#define COUT 128
#define KS   15
#define TP   32
#define WF_BYTES  245760u
#define FP_BYTES  (2u * MB * CIN * 2u)    // 4,194,304
#define SP4_BYTES (2u * MB * 16u)         //   524,288

typedef __attribute__((ext_vector_type(8))) short short8;
typedef __attribute__((ext_vector_type(4))) float f32x4;

// rotation-reduce step over the 16-lane DPP row: s += row_ror<n>(s)
#define ROR_ADD(s, ctrl) \
    ((s) + __int_as_float(__builtin_amdgcn_update_dpp( \
        0, __float_as_int(s), (ctrl), 0xF, 0xF, true)))

// bf16 pack (round-to-nearest, ties-away): low short = f0, high short = f1
static __device__ __forceinline__ unsigned int pack2_bf16(float f0, float f1) {
    const unsigned int a = __float_as_uint(f0) + 0x8000u;
    const unsigned int b = __float_as_uint(f1) + 0x8000u;
    return (a >> 16) | (b & 0xffff0000u);
}

static __device__ __forceinline__ unsigned int pack2_bf16_rne(float f0, float f1) {
    unsigned int a = __float_as_uint(f0);
    unsigned int b = __float_as_uint(f1);
    a += 0x7fffu + ((a >> 16) & 1u);
    b += 0x7fffu + ((b >> 16) & 1u);
    return (a >> 16) | (b & 0xffff0000u);
}

static __device__ __forceinline__ unsigned short f32_to_bf16_rne(float x) {
    unsigned int u = __float_as_uint(x);
    u += 0x7fffu + ((u >> 16) & 1u);
    return (unsigned short)(u >> 16);
}

__global__ __launch_bounds__(256)
void prep_kernel(const float* __restrict__ Wg, const float* __restrict__ feats,
                 const float* __restrict__ sp,
                 unsigned short* __restrict__ wf, unsigned int* __restrict__ fp,
                 float4* __restrict__ sp4, int full) {
    const int bid = blockIdx.x;
    if (bid < 60) {
        // W -> bf16 B-frag layout (15360 threads exactly)
        const int tid = bid * 256 + threadIdx.x;
        const int l = tid & 63;
        const int t = (tid >> 6) & 7;
        const int s = tid >> 9;
        const int n  = t * 16 + (l & 15);
        const int kb = s * 32 + (l >> 4) * 8;
        short8 o;
        #pragma unroll
        for (int i = 0; i < 8; ++i)
            o[i] = (short)f32_to_bf16_rne(Wg[(kb + i) * COUT + n]);
        *(short8*)(wf + (size_t)tid * 8) = o;
    } else if (!full) {
        return;
    } else if (bid < 60 + 128) {
        // support points -> float4 (32768 threads exactly)
        const int m = (bid - 60) * 256 + threadIdx.x;
        const float* s3 = sp + 3 * (size_t)m;
        sp4[m] = make_float4(s3[0], s3[1], s3[2], 0.0f);
    } else {
        // feats -> bf16 permuted: row m, position p=n16*4+t holds c=t*16+n16
        const unsigned int t = (unsigned int)(bid - 188) * 256u + threadIdx.x;
        if (t < 2u * MB * 32u) {          // u32 outputs: 32 per row
            const int m   = t >> 5;
            const int p2  = t & 31;       // output u32 = positions 2p2,2p2+1
            const int n16 = p2 >> 1;
            const int tt  = (p2 & 1) * 2;
            const float a = feats[(size_t)m * CIN + tt * 16 + n16];
            const float b = feats[(size_t)m * CIN + (tt + 1) * 16 + n16];
            fp[t] = pack2_bf16_rne(a, b);
        }
    }
}

// ---- straight-line building blocks (macro-expanded; no pointer locals) ----

#define LOAD_IDX_PAIR(IDX0, IDX1, GPH)                                        \
    {                                                                         \
        const int* ipp_ = nidx + (size_t)(GPH) * KN + quad * 8;               \
        *(int4*)(&IDX0[0]) = *(const int4*)(ipp_);                            \
        *(int4*)(&IDX0[4]) = *(const int4*)(ipp_ + 4);                        \
        *(int4*)(&IDX1[0]) = *(const int4*)(ipp_ + KN);                       \
        *(int4*)(&IDX1[4]) = *(const int4*)(ipp_ + KN + 4);                   \
    }

#define GATHER_SP4(IDXV, S4V)                                                 \
    {                                                                         \
        if (PK) {                                                             \
            _Pragma("unroll")                                                 \
            for (int i_ = 0; i_ < 8; ++i_) S4V[i_] = sp4b[IDXV[i_]];          \
        } else {                                                              \
            _Pragma("unroll")                                                 \
            for (int i_ = 0; i_ < 8; ++i_) {                                  \
                const float* s3_ = spb + (size_t)IDXV[i_] * 3;                \
                S4V[i_] = make_float4(s3_[0], s3_[1], s3_[2], 0.0f);          \
            }                                                                 \
        }                                                                     \
    }

#define A_POINT(IDXV, S4V, BASE, PLH, GP)                                     \
    {                                                                         \
        uint2 g_[8];                                                          \
        if (PK) {                                                             \
            _Pragma("unroll")                                                 \
            for (int i_ = 0; i_ < 8; ++i_)                                    \
                g_[i_] = *(const uint2*)(fpb + (size_t)IDXV[i_] * 32 + n16 * 2); \
        }                                                                     \
        const float qx_ = qp[3 * (GP) + 0];                                   \
        const float qy_ = qp[3 * (GP) + 1];                                   \
        const float qz_ = qp[3 * (GP) + 2];                                   \
        const float qkx_ = qx_ + kxj, qky_ = qy_ + kyj, qkz_ = qz_ + kzj;     \
        float e_[8];                                                          \
        _Pragma("unroll")                                                     \
        for (int i_ = 0; i_ < 8; ++i_) {                                      \
            const float dx_ = S4V[i_].x - qkx_;                               \
            const float dy_ = S4V[i_].y - qky_;                               \
            const float dz_ = S4V[i_].z - qkz_;                               \
            const float d2_ = fmaf(dx_, dx_, fmaf(dy_, dy_, dz_ * dz_));      \
            e_[i_] = __expf(-200.0f * d2_);                                   \
        }                                                                     \
        unsigned int iu_[4];                                                  \
        _Pragma("unroll")                                                     \
        for (int ih_ = 0; ih_ < 4; ++ih_) {                                   \
            float s0_ = e_[2 * ih_], s1_ = e_[2 * ih_ + 1];                   \
            s0_ = ROR_ADD(s0_, 0x128); s1_ = ROR_ADD(s1_, 0x128);             \
            s0_ = ROR_ADD(s0_, 0x124); s1_ = ROR_ADD(s1_, 0x124);             \
            s0_ = ROR_ADD(s0_, 0x122); s1_ = ROR_ADD(s1_, 0x122);             \
            s0_ = ROR_ADD(s0_, 0x121); s1_ = ROR_ADD(s1_, 0x121);             \
            const float n0_ = e_[2 * ih_]     * __builtin_amdgcn_rcpf(s0_ + 1e-6f); \
            const float n1_ = e_[2 * ih_ + 1] * __builtin_amdgcn_rcpf(s1_ + 1e-6f); \
            iu_[ih_] = pack2_bf16(n0_, n1_);                                  \
        }                                                                     \
        const short8 ifrag_ = *(const short8*)iu_;                            \
        unsigned int fu_[4][4];                                               \
        if (PK) {                                                             \
            _Pragma("unroll")                                                 \
            for (int ih_ = 0; ih_ < 4; ++ih_) {                               \
                const unsigned int ax_ = g_[2 * ih_].x, bx_ = g_[2 * ih_ + 1].x; \
                const unsigned int ay_ = g_[2 * ih_].y, by_ = g_[2 * ih_ + 1].y; \
                fu_[0][ih_] = __builtin_amdgcn_perm(bx_, ax_, 0x05040100u);   \
                fu_[1][ih_] = __builtin_amdgcn_perm(bx_, ax_, 0x07060302u);   \
                fu_[2][ih_] = __builtin_amdgcn_perm(by_, ay_, 0x05040100u);   \
                fu_[3][ih_] = __builtin_amdgcn_perm(by_, ay_, 0x07060302u);   \
            }                                                                 \
        } else {                                                              \
            _Pragma("unroll")                                                 \
            for (int ih_ = 0; ih_ < 4; ++ih_) {                               \
                const float* fr0_ = fbf + (size_t)IDXV[2 * ih_]     * CIN + n16; \
                const float* fr1_ = fbf + (size_t)IDXV[2 * ih_ + 1] * CIN + n16; \
                _Pragma("unroll")                                             \
                for (int t_ = 0; t_ < 4; ++t_)                                \
                    fu_[t_][ih_] = pack2_bf16(fr0_[t_ * 16], fr1_[t_ * 16]);  \
            }                                                                 \
        }                                                                     \
        _Pragma("unroll")                                                     \
        for (int t_ = 0; t_ < 4; ++t_) {                                      \
            const short8 ffrag_ = *(const short8*)(fu_[t_]);                  \
            f32x4 z_ = {0.f, 0.f, 0.f, 0.f};                                  \
            const f32x4 dd_ = __builtin_amdgcn_mfma_f32_16x16x32_bf16(        \
                ffrag_, ifrag_, z_, 0, 0, 0);                                 \
            const unsigned int lo_ = pack2_bf16(dd_[0], dd_[1]);              \
            const unsigned int hi_ = pack2_bf16(dd_[2], dd_[3]);              \
            const int off_ = n16 * 2048 + (t_ * 2 + (quad >> 1)) * 256 +      \
                             (((PLH) ^ (n16 & 7)) * 16) + (quad & 1) * 8;     \
            uint2 v_; v_.x = lo_; v_.y = hi_;                                 \
            *(uint2*)((BASE) + off_) = v_;                                    \
        }                                                                     \
    }

#define B_HALF(BASE, ROW0)                                                    \
    {                                                                         \
        f32x4 acc_ = {0.f, 0.f, 0.f, 0.f};                                    \
        _Pragma("unroll")                                                     \
        for (int s_ = 0; s_ < 30; ++s_) {                                     \
            const int j_ = s_ >> 1;                                           \
            const int u_ = (s_ & 1) * 4 + quad;                               \
            const short8 a_ = *(const short8*)((BASE) + j_ * 2048 + u_ * 256 +\
                                               ((n16 ^ (j_ & 7)) * 16));      \
            const short8 bf_ = *(const short8*)(wfrag +                       \
                                ((size_t)(s_ * 8 + wv) * 64 + lane) * 8);     \
            acc_ = __builtin_amdgcn_mfma_f32_16x16x32_bf16(a_, bf_, acc_, 0, 0, 0); \
        }                                                                     \
        _Pragma("unroll")                                                     \
        for (int r_ = 0; r_ < 4; ++r_)                                        \
            out[(size_t)((ROW0) + quad * 4 + r_) * COUT + wv * 16 + n16]      \
                = acc_[r_] + bsv;                                             \
    }

template<bool PK>
__global__ __launch_bounds__(512, 4)
void kpconv_mfma(const float* __restrict__ qp,
                 const float* __restrict__ sp,
                 const float* __restrict__ feats,
                 const unsigned int* __restrict__ fpk,
                 const float4* __restrict__ sp4,
                 const int* __restrict__ nidx,
                 const float* __restrict__ kp,
                 const unsigned short* __restrict__ wfrag,
                 const float* __restrict__ bias,
                 float* __restrict__ out) {
    __shared__ __align__(16) char sF[2 * 32768];   // 65536 B -> 2 blocks/CU

    const int tid  = threadIdx.x;
    const int lane = tid & 63;
    const int wv   = tid >> 6;                 // 0..7
    const int gp_base = blockIdx.x * TP;
    const int b = gp_base >> 14;
    const float*        fbf  = feats + (size_t)b * MB * CIN;
    const unsigned int* fpb  = fpk + (size_t)b * MB * 32;       // 32 u32/row
    const float4*       sp4b = sp4 + (size_t)b * MB;
    const float*        spb  = sp + (size_t)b * MB * 3;

    const int n16  = lane & 15;     // j (A) / point row (B read) / o-sub (B out)
    const int quad = lane >> 4;     // k-group selector

    // kernel point for this lane's j; j==15 pad -> sentinel far away so
    // exp(-200*d2) underflows to exactly 0
    float kxj, kyj, kzj;
    if (n16 < 15) {
        kxj = kp[3 * n16 + 0];
        kyj = kp[3 * n16 + 1];
        kzj = kp[3 * n16 + 2];
    } else {
        kxj = 1.0e4f; kyj = 1.0e4f; kzj = 1.0e4f;
    }
    const float bsv = bias[wv * 16 + n16];

    // ---------------- half 0 ----------------
    int idxA0[8], idxB0[8];
    float4 s4A0[8], s4B0[8];
    const int gph0 = gp_base + wv * 2;
    LOAD_IDX_PAIR(idxA0, idxB0, gph0);
    GATHER_SP4(idxA0, s4A0);
    GATHER_SP4(idxB0, s4B0);
    A_POINT(idxA0, s4A0, sF, wv * 2,     gph0);
    A_POINT(idxB0, s4B0, sF, wv * 2 + 1, gph0 + 1);
    __syncthreads();

    // ---------------- prefetch half 1, B(h0), A(h1) ----------------
    int idxA1[8], idxB1[8];
    float4 s4A1[8], s4B1[8];
    const int gph1 = gp_base + 16 + wv * 2;
    LOAD_IDX_PAIR(idxA1, idxB1, gph1);
    GATHER_SP4(idxA1, s4A1);
    GATHER_SP4(idxB1, s4B1);

    B_HALF(sF, gp_base);                       // reads sF[0]; h1 writes sF[1]

    A_POINT(idxA1, s4A1, sF + 32768, wv * 2,     gph1);
    A_POINT(idxB1, s4B1, sF + 32768, wv * 2 + 1, gph1 + 1);
    __syncthreads();

    // ---------------- B(h1) ----------------
    B_HALF(sF + 32768, gp_base + 16);
}

extern "C" void kernel_launch(void* const* d_in, const int* in_sizes, int n_in,
                              void* d_out, int out_size, void* d_ws, size_t ws_size,
                              hipStream_t stream) {
    const float* qp = (const float*)d_in[0];   // query_points   [B,N,3]
    const float* sp = (const float*)d_in[1];   // support_points [B,M,3]
    const float* ft = (const float*)d_in[2];   // support_features [B,M,C_IN]
    const int*   ni = (const int*)d_in[3];     // neighbor_idx   [B,N,K]
    const float* kp = (const float*)d_in[4];   // kernel_points  [KS,3]
    const float* wg = (const float*)d_in[5];   // weights        [KS,C_IN,C_OUT]
    const float* bs = (const float*)d_in[6];   // bias           [C_OUT]
    float* o = (float*)d_out;                  // [B,N,C_OUT] fp32

    unsigned short* wfrag = (unsigned short*)d_ws;
    unsigned int*   fpk   = (unsigned int*)((char*)d_ws + WF_BYTES);
    float4*         sp4   = (float4*)((char*)d_ws + WF_BYTES + FP_BYTES);
    const int full = (ws_size >= (size_t)(WF_BYTES + FP_BYTES + SP4_BYTES)) ? 1 : 0;

    const int prep_blocks = full ? (60 + 128 + 4096) : 60;
    hipLaunchKernelGGL(prep_kernel, dim3(prep_blocks), dim3(256), 0, stream,
                       wg, ft, sp, wfrag, fpk, sp4, full);

    if (full) {
        hipLaunchKernelGGL((kpconv_mfma<true>), dim3((2 * NB) / TP), dim3(512), 0, stream,
                           qp, sp, ft, fpk, sp4, ni, kp, wfrag, bs, o);
    } else {
        hipLaunchKernelGGL((kpconv_mfma<false>), dim3((2 * NB) / TP), dim3(512), 0, stream,
                           qp, sp, ft, fpk, sp4, ni, kp, wfrag, bs, o);
    }
}

// Round 11
// 108.844 us; speedup vs baseline: 1.2087x; 1.2063x over previous
//
#include <hip/hip_runtime.h>
#include <hip/hip_bf16.h>

// KPConv MI355X — Round 11: R8 structure (best known, 109.2 us) +
// pre-barrier W prefetch (phase-B steps 0..1 peeled; their L2 latency
// drains inside the __syncthreads vmcnt(0) wait). R9/R10's half-tile
// pipeline abandoned: live set forces scratch spills (WRITE 16->57 MB).
// B=2, N=16384, M=16384, K=32, C_IN=64, C_OUT=128, KS=15, sigma=0.05.
//
// LDS (16-B chunks): addr(j, u, pl) = j*4096 + u*512 + ((pl^(j&7))*16)
//   j = kernel pt 0..15 (15 pad), u = c-octet 0..7, pl = point 0..31.
//   Phase-A b64 writes: depth-4/bank floor. Phase-B b128 reads: depth-8 floor.
// Phase A (wave = 4 points, pipelined): sp4 gathers for pt+1 and idx for
//   pt+2 in flight during pt's compute; influences in B-frag layout
//   (sentinel pad j=15), DPP row_ror normalize, feats as uint2 + v_perm;
//   one 16x16x32 bf16 MFMA per c-tile; D -> bf16 -> LDS.
// Phase B: wave wv = n-tile wv, both m-tiles; 30 x (2 ds_read_b128 +
//   1 W b128 + 2 MFMA); W B-frags straight from L2 (245 KB/block).

#define NB   16384
#define MB   16384
#define KN   32
#define CIN  64
#define COUT 128
#define KS   15
#define TP   32
#define WF_BYTES  245760u
#define FP_BYTES  (2u * MB * CIN * 2u)    // 4,194,304
#define SP4_BYTES (2u * MB * 16u)         //   524,288

typedef __attribute__((ext_vector_type(8))) short short8;
typedef __attribute__((ext_vector_type(4))) float f32x4;

// rotation-reduce step over the 16-lane DPP row: s += row_ror<n>(s)
#define ROR_ADD(s, ctrl) \
    ((s) + __int_as_float(__builtin_amdgcn_update_dpp( \
        0, __float_as_int(s), (ctrl), 0xF, 0xF, true)))

// bf16 pack (round-to-nearest, ties-away): low short = f0, high short = f1
static __device__ __forceinline__ unsigned int pack2_bf16(float f0, float f1) {
    const unsigned int a = __float_as_uint(f0) + 0x8000u;
    const unsigned int b = __float_as_uint(f1) + 0x8000u;
    return (a >> 16) | (b & 0xffff0000u);
}

static __device__ __forceinline__ unsigned int pack2_bf16_rne(float f0, float f1) {
    unsigned int a = __float_as_uint(f0);
    unsigned int b = __float_as_uint(f1);
    a += 0x7fffu + ((a >> 16) & 1u);
    b += 0x7fffu + ((b >> 16) & 1u);
    return (a >> 16) | (b & 0xffff0000u);
}

static __device__ __forceinline__ unsigned short f32_to_bf16_rne(float x) {
    unsigned int u = __float_as_uint(x);
    u += 0x7fffu + ((u >> 16) & 1u);
    return (unsigned short)(u >> 16);
}

__global__ __launch_bounds__(256)
void prep_kernel(const float* __restrict__ Wg, const float* __restrict__ feats,
                 const float* __restrict__ sp,
                 unsigned short* __restrict__ wf, unsigned int* __restrict__ fp,
                 float4* __restrict__ sp4, int full) {
    const int bid = blockIdx.x;
    if (bid < 60) {
        // W -> bf16 B-frag layout (15360 threads exactly)
        const int tid = bid * 256 + threadIdx.x;
        const int l = tid & 63;
        const int t = (tid >> 6) & 7;
        const int s = tid >> 9;
        const int n  = t * 16 + (l & 15);
        const int kb = s * 32 + (l >> 4) * 8;
        short8 o;
        #pragma unroll
        for (int i = 0; i < 8; ++i)
            o[i] = (short)f32_to_bf16_rne(Wg[(kb + i) * COUT + n]);
        *(short8*)(wf + (size_t)tid * 8) = o;
    } else if (!full) {
        return;
    } else if (bid < 60 + 128) {
        // support points -> float4 (32768 threads exactly)
        const int m = (bid - 60) * 256 + threadIdx.x;
        const float* s3 = sp + 3 * (size_t)m;
        sp4[m] = make_float4(s3[0], s3[1], s3[2], 0.0f);
    } else {
        // feats -> bf16 permuted: row m, position p=n16*4+t holds c=t*16+n16
        const unsigned int t = (unsigned int)(bid - 188) * 256u + threadIdx.x;
        if (t < 2u * MB * 32u) {          // u32 outputs: 32 per row
            const int m   = t >> 5;
            const int p2  = t & 31;       // output u32 = positions 2p2,2p2+1
            const int n16 = p2 >> 1;
            const int tt  = (p2 & 1) * 2;
            const float a = feats[(size_t)m * CIN + tt * 16 + n16];
            const float b = feats[(size_t)m * CIN + (tt + 1) * 16 + n16];
            fp[t] = pack2_bf16_rne(a, b);
        }
    }
}

template<bool PK>
__global__ __launch_bounds__(512, 4)
void kpconv_mfma(const float* __restrict__ qp,
                 const float* __restrict__ sp,
                 const float* __restrict__ feats,
                 const unsigned int* __restrict__ fpk,
                 const float4* __restrict__ sp4,
                 const int* __restrict__ nidx,
                 const float* __restrict__ kp,
                 const unsigned short* __restrict__ wfrag,
                 const float* __restrict__ bias,
                 float* __restrict__ out) {
    __shared__ __align__(16) char sF[16 * 4096];   // 65536 B -> 2 blocks/CU

    const int tid  = threadIdx.x;
    const int lane = tid & 63;
    const int wv   = tid >> 6;                 // 0..7
    const int gp_base = blockIdx.x * TP;
    const int b = gp_base >> 14;
    const float*        fbf  = feats + (size_t)b * MB * CIN;
    const unsigned int* fpb  = fpk + (size_t)b * MB * 32;       // 32 u32/row
    const float4*       sp4b = sp4 + (size_t)b * MB;
    const float*        spb  = sp + (size_t)b * MB * 3;

    const int n16  = lane & 15;     // j (influence col) / c-sub / pt-in-tile
    const int quad = lane >> 4;     // k-group selector

    // kernel point for this lane's j; j==15 pad -> sentinel far away so
    // exp(-200*d2) underflows to exactly 0
    float kxj, kyj, kzj;
    if (n16 < 15) {
        kxj = kp[3 * n16 + 0];
        kyj = kp[3 * n16 + 1];
        kzj = kp[3 * n16 + 2];
    } else {
        kxj = 1.0e4f; kyj = 1.0e4f; kzj = 1.0e4f;
    }

    // ---------------- Phase A: 4 points per wave, pipelined ----------------
    const int gp0 = gp_base + wv * 4;
    const int* ip = nidx + (size_t)gp0 * KN + quad * 8;

    int idxc[8], idxn[8];
    *(int4*)(&idxc[0]) = *(const int4*)(ip);
    *(int4*)(&idxc[4]) = *(const int4*)(ip + 4);

    // prefetch pt0 support points
    float4 s4c[8];
    if (PK) {
        #pragma unroll
        for (int i = 0; i < 8; ++i) s4c[i] = sp4b[idxc[i]];
    }
    *(int4*)(&idxn[0]) = *(const int4*)(ip + KN);
    *(int4*)(&idxn[4]) = *(const int4*)(ip + KN + 4);

    #pragma unroll
    for (int pt = 0; pt < 4; ++pt) {
        const int pl = wv * 4 + pt;
        const int gp = gp0 + pt;

        // current point's feat gathers (consumed late -> self-hiding)
        uint2 g[8];
        if (PK) {
            #pragma unroll
            for (int i = 0; i < 8; ++i)
                g[i] = *(const uint2*)(fpb + (size_t)idxc[i] * 32 + n16 * 2);
        }

        // prefetch next point's support points; idx for pt+2
        float4 s4n[8];
        if (PK && pt < 3) {
            #pragma unroll
            for (int i = 0; i < 8; ++i) s4n[i] = sp4b[idxn[i]];
        }
        int idx2[8];
        if (pt < 2) {
            const int* ip2 = ip + (pt + 2) * KN;
            *(int4*)(&idx2[0]) = *(const int4*)(ip2);
            *(int4*)(&idx2[4]) = *(const int4*)(ip2 + 4);
        }

        const float qx = qp[3 * gp + 0];
        const float qy = qp[3 * gp + 1];
        const float qz = qp[3 * gp + 2];
        const float qkx = qx + kxj, qky = qy + kyj, qkz = qz + kzj;

        float e[8];
        if (PK) {
            #pragma unroll
            for (int i = 0; i < 8; ++i) {
                const float dx = s4c[i].x - qkx;
                const float dy = s4c[i].y - qky;
                const float dz = s4c[i].z - qkz;
                const float d2 = fmaf(dx, dx, fmaf(dy, dy, dz * dz));
                e[i] = __expf(-200.0f * d2);   // 1/(2*sigma^2); j=15 -> 0
            }
        } else {
            #pragma unroll
            for (int i = 0; i < 8; ++i) {
                const float* s3 = spb + (size_t)idxc[i] * 3;
                const float dx = s3[0] - qkx;
                const float dy = s3[1] - qky;
                const float dz = s3[2] - qkz;
                const float d2 = fmaf(dx, dx, fmaf(dy, dy, dz * dz));
                e[i] = __expf(-200.0f * d2);
            }
        }

        // normalize over j = 16-lane DPP row (pure VALU)
        unsigned int iu[4];
        float en[8];
        #pragma unroll
        for (int i = 0; i < 8; ++i) {
            float s = e[i];
            s = ROR_ADD(s, 0x128);   // row_ror:8
            s = ROR_ADD(s, 0x124);   // row_ror:4
            s = ROR_ADD(s, 0x122);   // row_ror:2
            s = ROR_ADD(s, 0x121);   // row_ror:1
            en[i] = e[i] * __builtin_amdgcn_rcpf(s + 1e-6f);
        }
        #pragma unroll
        for (int ih = 0; ih < 4; ++ih)
            iu[ih] = pack2_bf16(en[2 * ih], en[2 * ih + 1]);
        const short8 ifrag = *(const short8*)iu;

        // feats A-frags: elem i = feat[idx[quad*8+i]][c=t*16+n16]
        unsigned int fu[4][4];
        if (PK) {
            #pragma unroll
            for (int ih = 0; ih < 4; ++ih) {
                const unsigned int ax = g[2 * ih].x, bx = g[2 * ih + 1].x;
                const unsigned int ay = g[2 * ih].y, by = g[2 * ih + 1].y;
                fu[0][ih] = __builtin_amdgcn_perm(bx, ax, 0x05040100u);
                fu[1][ih] = __builtin_amdgcn_perm(bx, ax, 0x07060302u);
                fu[2][ih] = __builtin_amdgcn_perm(by, ay, 0x05040100u);
                fu[3][ih] = __builtin_amdgcn_perm(by, ay, 0x07060302u);
            }
        } else {
            #pragma unroll
            for (int ih = 0; ih < 4; ++ih) {
                const float* fr0 = fbf + (size_t)idxc[2 * ih]     * CIN + n16;
                const float* fr1 = fbf + (size_t)idxc[2 * ih + 1] * CIN + n16;
                #pragma unroll
                for (int t = 0; t < 4; ++t)
                    fu[t][ih] = pack2_bf16(fr0[t * 16], fr1[t * 16]);
            }
        }

        // MFMA per c-tile t; D[c_local=quad*4+r][j=n16] -> b64 store:
        // chunk u = t*2+(quad>>1), half quad&1, row swizzle pl^(n16&7)
        #pragma unroll
        for (int t = 0; t < 4; ++t) {
            const short8 ffrag = *(const short8*)(fu[t]);
            f32x4 z = {0.f, 0.f, 0.f, 0.f};
            const f32x4 dd = __builtin_amdgcn_mfma_f32_16x16x32_bf16(ffrag, ifrag, z, 0, 0, 0);
            const unsigned int lo = pack2_bf16(dd[0], dd[1]);
            const unsigned int hi = pack2_bf16(dd[2], dd[3]);
            const int off = n16 * 4096 + (t * 2 + (quad >> 1)) * 512 +
                            ((pl ^ (n16 & 7)) * 16) + (quad & 1) * 8;
            uint2 v; v.x = lo; v.y = hi;
            *(uint2*)(sF + off) = v;                  // ds_write_b64
        }

        // rotate pipeline registers
        if (pt < 3) {
            #pragma unroll
            for (int i = 0; i < 8; ++i) {
                if (PK) s4c[i] = s4n[i];
                idxc[i] = idxn[i];
            }
            if (pt < 2) {
                #pragma unroll
                for (int i = 0; i < 8; ++i) idxn[i] = idx2[i];
            }
        }
    }

    // pre-barrier W prefetch: s=0 and s=1 fragments. Their L2 latency
    // drains inside the compiler's vmcnt(0)+s_barrier wait. +8 VGPRs only.
    const short8 wpre0 = *(const short8*)(wfrag + ((size_t)(0 * 8 + wv) * 64 + lane) * 8);
    const short8 wpre1 = *(const short8*)(wfrag + ((size_t)(1 * 8 + wv) * 64 + lane) * 8);
    __syncthreads();

    // --- Phase B: wave wv = n-tile; 30 x (2 ds_read_b128 + 1 W b128 + 2 MFMA) ---
    f32x4 acc0 = {0.f, 0.f, 0.f, 0.f};
    f32x4 acc1 = {0.f, 0.f, 0.f, 0.f};

    // peeled s=0 (j=0, u=quad) — uses wpre0
    {
        const int off0 = quad * 512 + (n16 * 16);
        const short8 a0 = *(const short8*)(sF + off0);
        const short8 a1 = *(const short8*)(sF + off0 + 256);
        acc0 = __builtin_amdgcn_mfma_f32_16x16x32_bf16(a0, wpre0, acc0, 0, 0, 0);
        acc1 = __builtin_amdgcn_mfma_f32_16x16x32_bf16(a1, wpre0, acc1, 0, 0, 0);
    }
    // peeled s=1 (j=0, u=4+quad) — uses wpre1
    {
        const int off0 = (4 + quad) * 512 + (n16 * 16);
        const short8 a0 = *(const short8*)(sF + off0);
        const short8 a1 = *(const short8*)(sF + off0 + 256);
        acc0 = __builtin_amdgcn_mfma_f32_16x16x32_bf16(a0, wpre1, acc0, 0, 0, 0);
        acc1 = __builtin_amdgcn_mfma_f32_16x16x32_bf16(a1, wpre1, acc1, 0, 0, 0);
    }

    #pragma unroll
    for (int s = 2; s < 30; ++s) {
        const int j = s >> 1;
        const int u = (s & 1) * 4 + quad;
        const int off0 = j * 4096 + u * 512 + ((n16 ^ (j & 7)) * 16);
        const short8 a0 = *(const short8*)(sF + off0);
        const short8 a1 = *(const short8*)(sF + off0 + 256);   // pl += 16
        const short8 bf = *(const short8*)(wfrag + ((size_t)(s * 8 + wv) * 64 + lane) * 8);
        acc0 = __builtin_amdgcn_mfma_f32_16x16x32_bf16(a0, bf, acc0, 0, 0, 0);
        acc1 = __builtin_amdgcn_mfma_f32_16x16x32_bf16(a1, bf, acc1, 0, 0, 0);
    }

    const float bsv = bias[wv * 16 + n16];
    #pragma unroll
    for (int r = 0; r < 4; ++r) {
        const int pr = quad * 4 + r;
        out[(size_t)(gp_base + pr)      * COUT + wv * 16 + n16] = acc0[r] + bsv;
        out[(size_t)(gp_base + 16 + pr) * COUT + wv * 16 + n16] = acc1[r] + bsv;
    }
}

extern "C" void kernel_launch(void* const* d_in, const int* in_sizes, int n_in,
                              void* d_out, int out_size, void* d_ws, size_t ws_size,
                              hipStream_t stream) {
    const float* qp = (const float*)d_in[0];   // query_points   [B,N,3]
    const float* sp = (const float*)d_in[1];   // support_points [B,M,3]
    const float* ft = (const float*)d_in[2];   // support_features [B,M,C_IN]
    const int*   ni = (const int*)d_in[3];     // neighbor_idx   [B,N,K]
    const float* kp = (const float*)d_in[4];   // kernel_points  [KS,3]
    const float* wg = (const float*)d_in[5];   // weights        [KS,C_IN,C_OUT]
    const float* bs = (const float*)d_in[6];   // bias           [C_OUT]
    float* o = (float*)d_out;                  // [B,N,C_OUT] fp32

    unsigned short* wfrag = (unsigned short*)d_ws;
    unsigned int*   fpk   = (unsigned int*)((char*)d_ws + WF_BYTES);
    float4*         sp4   = (float4*)((char*)d_ws + WF_BYTES + FP_BYTES);
    const int full = (ws_size >= (size_t)(WF_BYTES + FP_BYTES + SP4_BYTES)) ? 1 : 0;

    const int prep_blocks = full ? (60 + 128 + 4096) : 60;
    hipLaunchKernelGGL(prep_kernel, dim3(prep_blocks), dim3(256), 0, stream,
                       wg, ft, sp, wfrag, fpk, sp4, full);

    if (full) {
        hipLaunchKernelGGL((kpconv_mfma<true>), dim3((2 * NB) / TP), dim3(512), 0, stream,
                           qp, sp, ft, fpk, sp4, ni, kp, wfrag, bs, o);
    } else {
        hipLaunchKernelGGL((kpconv_mfma<false>), dim3((2 * NB) / TP), dim3(512), 0, stream,
                           qp, sp, ft, fpk, sp4, ni, kp, wfrag, bs, o);
    }
}